// Round 8
// baseline (759.677 us; speedup 1.0000x reference)
//
#include <hip/hip_runtime.h>
#include <hip/hip_bf16.h>
#include <stdint.h>

typedef float  f32x4  __attribute__((ext_vector_type(4)));
typedef __bf16 bf16x8 __attribute__((ext_vector_type(8)));

#define WSB 131072      // quantized-B frag table: 8192 frags * 16 B

// exp_proj onto {sign(w) * 0.25 * 2^k, k=0..4}; boundaries at 0.25*2^(k+0.5)
__device__ __forceinline__ float qlog(float v) {
    float a = fabsf(v);
    int k = (a >= 0.35355339059327373f)
          + (a >= 0.70710678118654746f)
          + (a >= 1.41421356237309515f)
          + (a >= 2.82842712474619029f);
    float q = 0.25f * (float)(1 << k);
    return (v == 0.0f) ? 0.0f : copysignf(q, v);
}

// kernel 1: quantize weight -> bf16 frag table in ws.
// frag id = (ntile*8 + kt)*64 + lane ; holds w_q[n][k0..k0+7],
// n = ntile*16 + (lane&15), k0 = kt*32 + (lane>>4)*8.
__global__ __launch_bounds__(256) void lqw_quant(
    const float* __restrict__ w, __hip_bfloat16* __restrict__ wsq)
{
    const int gid  = blockIdx.x * 256 + threadIdx.x;   // 0..8191
    const int lane = gid & 63;
    const int kt   = (gid >> 6) & 7;
    const int ntv  = gid >> 9;                         // 0..15
    const float* src = w + (size_t)(ntv * 16 + (lane & 15)) * 256
                         + kt * 32 + (lane >> 4) * 8;
    bf16x8 fr;
    #pragma unroll
    for (int e = 0; e < 8; ++e) fr[e] = (__bf16)qlog(src[e]);
    *(bf16x8*)((char*)wsq + (size_t)gid * 16) = fr;
}

// kernel 2: free-running GEMM. No LDS, no barriers.
// Each wave owns 4 consecutive row-tiles of 16 rows x all 256 cols.
// B fragments stream from the L1/L2-resident ws table at point of use.
template<bool USE_WS>
__global__ __launch_bounds__(256, 4) void lqw_gemm(
    const float* __restrict__ in,    // [262144][256]
    const float* __restrict__ w,     // [256][256]
    const float* __restrict__ bias,  // [256]
    const __hip_bfloat16* __restrict__ wsq,
    float* __restrict__ out)         // [262144][256]
{
    const int tid  = threadIdx.x;
    const int lane = tid & 63;
    const int wv   = tid >> 6;                    // 0..3
    const int gw   = blockIdx.x * 4 + wv;         // 0..4095
    const int lrow = lane & 15;
    const int kgrp = lane >> 4;
    const bf16x8* wq = (const bf16x8*)wsq;

    #pragma unroll 1
    for (int i = 0; i < 4; ++i) {
        const int    rt = gw * 4 + i;             // row-tile 0..16383
        const size_t rb = (size_t)rt * 16;        // first row of tile
        const float* arow = in + (rb + lrow) * 256 + kgrp * 8;

        // acc init with bias: lane holds n = nt*16 + kgrp*4 + rg (swapped-D)
        f32x4 acc[16];
        #pragma unroll
        for (int nt = 0; nt < 16; ++nt)
            acc[nt] = *(const f32x4*)(bias + nt * 16 + kgrp * 4);

        #pragma unroll
        for (int kt = 0; kt < 8; ++kt) {
            // A fragment: lane = 32 contiguous bytes of row rb+lrow
            f32x4 a0 = *(const f32x4*)(arow + kt * 32);
            f32x4 a1 = *(const f32x4*)(arow + kt * 32 + 4);
            bf16x8 af;
            #pragma unroll
            for (int e = 0; e < 4; ++e) { af[e] = (__bf16)a0[e]; af[4 + e] = (__bf16)a1[e]; }

            #pragma unroll
            for (int nt = 0; nt < 16; ++nt) {
                bf16x8 bf_;
                if (USE_WS) {
                    bf_ = wq[(size_t)(nt * 8 + kt) * 64 + lane];   // 1 KB/wave, L1/L2-hot
                } else {
                    const float* wrow = w + (size_t)(nt * 16 + lrow) * 256 + kt * 32 + kgrp * 8;
                    #pragma unroll
                    for (int e = 0; e < 8; ++e) bf_[e] = (__bf16)qlog(wrow[e]);
                }
                // swapped operands: D[i=n][j=m]
                acc[nt] = __builtin_amdgcn_mfma_f32_16x16x32_bf16(bf_, af, acc[nt], 0, 0, 0);
            }
        }

        // store: row m = rb + lrow, cols nt*16 + kgrp*4 .. +3
        float* orow = out + (rb + lrow) * 256 + kgrp * 4;
        #pragma unroll
        for (int nt = 0; nt < 16; ++nt)
            *(f32x4*)(orow + nt * 16) = acc[nt];
    }
}

extern "C" void kernel_launch(void* const* d_in, const int* in_sizes, int n_in,
                              void* d_out, int out_size, void* d_ws, size_t ws_size,
                              hipStream_t stream) {
    const float* in_p   = (const float*)d_in[0];
    const float* w_p    = (const float*)d_in[1];
    const float* bias_p = (const float*)d_in[2];
    float* out_p        = (float*)d_out;
    if (ws_size >= WSB) {
        __hip_bfloat16* wsq = (__hip_bfloat16*)d_ws;
        lqw_quant<<<32, 256, 0, stream>>>(w_p, wsq);
        lqw_gemm<true><<<1024, 256, 0, stream>>>(in_p, w_p, bias_p, wsq, out_p);
    } else {
        lqw_gemm<false><<<1024, 256, 0, stream>>>(in_p, w_p, bias_p, nullptr, out_p);
    }
}

// Round 9
// 137.877 us; speedup vs baseline: 5.5098x; 5.5098x over previous
//
#include <hip/hip_runtime.h>
#include <hip/hip_bf16.h>
#include <stdint.h>

typedef float  f32x4  __attribute__((ext_vector_type(4)));
typedef __bf16 bf16x8 __attribute__((ext_vector_type(8)));
typedef __bf16 bf16x4 __attribute__((ext_vector_type(4)));

#define GRID   1024
#define MROWS  32
#define ITERS  8           // GRID * ITERS * MROWS = 262144 rows
#define ROWB   528         // bf16 LDS row stride in bytes (512 + 16 pad)
#define TILEB  (MROWS * ROWB)
#define WSB    131072      // quantized-B frag table: 8192 frags * 16 B

// raw barrier: ds ops visible, vmem NOT drained (loads/stores live across it)
#define BAR() do {                                         \
    asm volatile("s_waitcnt lgkmcnt(0)" ::: "memory");     \
    __builtin_amdgcn_s_barrier();                          \
} while (0)

// exp_proj onto {sign(w) * 0.25 * 2^k, k=0..4}; boundaries at 0.25*2^(k+0.5)
__device__ __forceinline__ float qlog(float v) {
    float a = fabsf(v);
    int k = (a >= 0.35355339059327373f)
          + (a >= 0.70710678118654746f)
          + (a >= 1.41421356237309515f)
          + (a >= 2.82842712474619029f);
    float q = 0.25f * (float)(1 << k);
    return (v == 0.0f) ? 0.0f : copysignf(q, v);
}

// kernel 1: quantize weight -> bf16 frag table in ws.
// frag id = ((wv*2+nt)*8 + kt)*64 + lane ; holds w_q[n][k0..k0+7],
// n = (wv*2+nt)*16 + (lane&15), k0 = kt*32 + (lane>>4)*8.
__global__ __launch_bounds__(256) void lqw_quant(
    const float* __restrict__ w, __hip_bfloat16* __restrict__ wsq)
{
    const int gid  = blockIdx.x * 256 + threadIdx.x;   // 0..8191
    const int lane = gid & 63;
    const int kt   = (gid >> 6) & 7;
    const int ntv  = gid >> 9;                         // 0..15
    const float* src = w + (size_t)(ntv * 16 + (lane & 15)) * 256
                         + kt * 32 + (lane >> 4) * 8;
    bf16x8 fr;
    #pragma unroll
    for (int e = 0; e < 8; ++e) fr[e] = (__bf16)qlog(src[e]);
    *(bf16x8*)((char*)wsq + (size_t)gid * 16) = fr;
}

template<bool USE_WS>
__global__ __launch_bounds__(512, 4) void lqw_gemm(
    const float* __restrict__ in,    // [262144][256]
    const float* __restrict__ w,     // [256][256]
    const float* __restrict__ bias,  // [256]
    const __hip_bfloat16* __restrict__ wsq,
    float* __restrict__ out)         // [262144][256]
{
    __shared__ __align__(16) char smem[2 * TILEB];   // 33792 B: 4 blocks/CU possible
    const int tid  = threadIdx.x;
    const int lane = tid & 63;
    const int wv   = tid >> 6;       // wave 0..7 owns 32 output cols
    const int nbase = wv * 32;
    const int lrow = lane & 15;
    const int kgrp = lane >> 4;

    // ---- quantized B fragments: coalesced load from ws (or self-quant) ----
    bf16x8 bq[2][8];
    if (USE_WS) {
        const bf16x8* wq = (const bf16x8*)wsq;
        #pragma unroll
        for (int nt = 0; nt < 2; ++nt)
            #pragma unroll
            for (int kt = 0; kt < 8; ++kt)
                bq[nt][kt] = wq[(size_t)((wv * 2 + nt) * 8 + kt) * 64 + lane];
    } else {
        #pragma unroll
        for (int nt = 0; nt < 2; ++nt) {
            const float* wrow = w + (size_t)(nbase + nt * 16 + lrow) * 256;
            #pragma unroll
            for (int kt = 0; kt < 8; ++kt) {
                bf16x8 fr;
                #pragma unroll
                for (int e = 0; e < 8; ++e)
                    fr[e] = (__bf16)qlog(wrow[kt * 32 + kgrp * 8 + e]);
                bq[nt][kt] = fr;
            }
        }
    }
    // bias for swapped-D layout: lane holds n = nbase + nt*16 + kgrp*4 + rg
    f32x4 bv[2];
    #pragma unroll
    for (int nt = 0; nt < 2; ++nt)
        bv[nt] = *(const f32x4*)(bias + nbase + nt * 16 + kgrp * 4);

    const int mt0 = blockIdx.x * ITERS;

    #define LOAD_TILE(S, mt) do {                                          \
        const f32x4* _s = (const f32x4*)(in + (size_t)(mt) * (MROWS*256)); \
        S[0] = _s[0*512 + tid]; S[1] = _s[1*512 + tid];                    \
        S[2] = _s[2*512 + tid]; S[3] = _s[3*512 + tid];                    \
    } while (0)

    #define WRITE_TILE(b, S) do {                                          \
        char* _d = smem + (b) * TILEB;                                     \
        _Pragma("unroll")                                                  \
        for (int r = 0; r < 4; ++r) {                                      \
            int j = r * 512 + tid;                                         \
            bf16x4 v;                                                      \
            v[0] = (__bf16)S[r][0]; v[1] = (__bf16)S[r][1];                \
            v[2] = (__bf16)S[r][2]; v[3] = (__bf16)S[r][3];                \
            *(bf16x4*)(_d + (j >> 6) * ROWB + (j & 63) * 8) = v;           \
        }                                                                  \
    } while (0)

    #define COMPUTE(b, mt) do {                                                             \
        const char* base = smem + (b) * TILEB;                                              \
        f32x4 acc[2][2];                                                                    \
        _Pragma("unroll")                                                                   \
        for (int mi = 0; mi < 2; ++mi)                                                      \
            _Pragma("unroll")                                                               \
            for (int nt = 0; nt < 2; ++nt) acc[mi][nt] = bv[nt];                            \
        _Pragma("unroll")                                                                   \
        for (int kt = 0; kt < 8; ++kt) {                                                    \
            bf16x8 a0 = *(const bf16x8*)(base + (size_t)lrow * ROWB + kt * 64 + kgrp * 16); \
            bf16x8 a1 = *(const bf16x8*)(base + (size_t)(16 + lrow) * ROWB + kt * 64 + kgrp * 16); \
            acc[0][0] = __builtin_amdgcn_mfma_f32_16x16x32_bf16(bq[0][kt], a0, acc[0][0], 0, 0, 0); \
            acc[0][1] = __builtin_amdgcn_mfma_f32_16x16x32_bf16(bq[1][kt], a0, acc[0][1], 0, 0, 0); \
            acc[1][0] = __builtin_amdgcn_mfma_f32_16x16x32_bf16(bq[0][kt], a1, acc[1][0], 0, 0, 0); \
            acc[1][1] = __builtin_amdgcn_mfma_f32_16x16x32_bf16(bq[1][kt], a1, acc[1][1], 0, 0, 0); \
        }                                                                                   \
        _Pragma("unroll")                                                                   \
        for (int mi = 0; mi < 2; ++mi) {                                                    \
            float* orow = out + (size_t)((mt) * 32 + mi * 16 + lrow) * 256 + nbase + kgrp * 4; \
            *(f32x4*)(orow)      = acc[mi][0];                                              \
            *(f32x4*)(orow + 16) = acc[mi][1];                                              \
        }                                                                                   \
    } while (0)

    // ---- 2-deep pipelined prologue ----
    f32x4 sA[4], sB[4];
    LOAD_TILE(sA, mt0);
    LOAD_TILE(sB, mt0 + 1);
    WRITE_TILE(0, sA);
    LOAD_TILE(sA, mt0 + 2);
    BAR();

    #pragma unroll 1
    for (int t = 0; t < ITERS; t += 2) {
        // even phase: compute tile t from buf0; stage t+1; prefetch t+3
        WRITE_TILE(1, sB);
        if (t + 3 < ITERS) LOAD_TILE(sB, mt0 + t + 3);
        COMPUTE(0, mt0 + t);
        BAR();
        // odd phase: compute tile t+1 from buf1; stage t+2; prefetch t+4
        if (t + 2 < ITERS) WRITE_TILE(0, sA);
        if (t + 4 < ITERS) LOAD_TILE(sA, mt0 + t + 4);
        COMPUTE(1, mt0 + t + 1);
        BAR();
    }
}

extern "C" void kernel_launch(void* const* d_in, const int* in_sizes, int n_in,
                              void* d_out, int out_size, void* d_ws, size_t ws_size,
                              hipStream_t stream) {
    const float* in_p   = (const float*)d_in[0];
    const float* w_p    = (const float*)d_in[1];
    const float* bias_p = (const float*)d_in[2];
    float* out_p        = (float*)d_out;
    if (ws_size >= WSB) {
        __hip_bfloat16* wsq = (__hip_bfloat16*)d_ws;
        lqw_quant<<<32, 256, 0, stream>>>(w_p, wsq);
        lqw_gemm<true><<<GRID, 512, 0, stream>>>(in_p, w_p, bias_p, wsq, out_p);
    } else {
        lqw_gemm<false><<<GRID, 512, 0, stream>>>(in_p, w_p, bias_p, nullptr, out_p);
    }
}

// Round 12
// 136.765 us; speedup vs baseline: 5.5546x; 1.0081x over previous
//
#include <hip/hip_runtime.h>
#include <hip/hip_bf16.h>
#include <stdint.h>

typedef float  f32x4  __attribute__((ext_vector_type(4)));
typedef __bf16 bf16x8 __attribute__((ext_vector_type(8)));
typedef __bf16 bf16x4 __attribute__((ext_vector_type(4)));
typedef unsigned int u32;
typedef u32 u32v2 __attribute__((ext_vector_type(2)));

#define GRID   1024
#define MROWS  32
#define ITERS  8           // GRID * ITERS * MROWS = 262144 rows
#define ROWB   528         // bf16 LDS row stride in bytes (512 + 16 pad)
#define TILEB  (MROWS * ROWB)
#define WSB    65536       // code table: 8192 frags * 8 B

// raw barrier: ds ops visible, vmem NOT drained (loads/stores live across it)
#define BAR() do {                                         \
    asm volatile("s_waitcnt lgkmcnt(0)" ::: "memory");     \
    __builtin_amdgcn_s_barrier();                          \
} while (0)

// exp_proj onto {sign(w) * 0.25 * 2^k, k=0..4}; boundaries at 0.25*2^(k+0.5)
__device__ __forceinline__ float qlog(float v) {
    float a = fabsf(v);
    int k = (a >= 0.35355339059327373f)
          + (a >= 0.70710678118654746f)
          + (a >= 1.41421356237309515f)
          + (a >= 2.82842712474619029f);
    float q = 0.25f * (float)(1 << k);
    return (v == 0.0f) ? 0.0f : copysignf(q, v);
}

// 1-byte code: sign<<7 | (bf16_exponent - 64). Grid exps are 125..129 -> 61..65.
// zero -> code 0 (decodes to 2^-63, negligible).
__device__ __forceinline__ u32 enc1(float q) {
    u32 b16 = __float_as_uint(q) >> 16;     // exact bf16 bits (powers of 2)
    return b16 ? (((b16 >> 8) & 0x80u) | (((b16 >> 7) & 0xFFu) - 64u)) : 0u;
}

// decode 2 codes in u16 lanes of d: bf16 = (code + (code&0x80) + 64) << 7
__device__ __forceinline__ u32 dec2(u32 d) {
    u32 t = d & 0x00800080u;
    return (d + t + 0x00400040u) << 7;
}
__device__ __forceinline__ bf16x8 dec_frag(u32 c0, u32 c1) {
#if __has_builtin(__builtin_amdgcn_perm)
    u32 d0 = __builtin_amdgcn_perm(0u, c0, 0x0C010C00u);   // [b0, b1] u16 lanes
    u32 d1 = __builtin_amdgcn_perm(0u, c0, 0x0C030C02u);   // [b2, b3]
    u32 d2 = __builtin_amdgcn_perm(0u, c1, 0x0C010C00u);
    u32 d3 = __builtin_amdgcn_perm(0u, c1, 0x0C030C02u);
#else
    u32 d0 = (c0 & 0xFFu) | ((c0 & 0xFF00u) << 8);
    u32 d1 = ((c0 >> 16) & 0xFFu) | ((c0 & 0xFF000000u) >> 8);
    u32 d2 = (c1 & 0xFFu) | ((c1 & 0xFF00u) << 8);
    u32 d3 = ((c1 >> 16) & 0xFFu) | ((c1 & 0xFF000000u) >> 8);
#endif
    union { u32 u[4]; bf16x8 v; } u_;
    u_.u[0] = dec2(d0); u_.u[1] = dec2(d1);
    u_.u[2] = dec2(d2); u_.u[3] = dec2(d3);
    return u_.v;
}

// kernel 1: quantize weight -> 1-byte-code frag table in ws.
// frag id f = (ntile*8 + kt)*64 + lane ; holds codes of w_q[n][k0..k0+7],
// n = ntile*16 + (lane&15), k0 = kt*32 + (lane>>4)*8.
__global__ __launch_bounds__(256) void lqw_quant(
    const float* __restrict__ w, u32v2* __restrict__ wsq)
{
    const int gid  = blockIdx.x * 256 + threadIdx.x;   // 0..8191
    const int lane = gid & 63;
    const int kt   = (gid >> 6) & 7;
    const int ntv  = gid >> 9;                         // 0..15
    const float* src = w + (size_t)(ntv * 16 + (lane & 15)) * 256
                         + kt * 32 + (lane >> 4) * 8;
    u32v2 c = (u32v2){0, 0};
    #pragma unroll
    for (int e = 0; e < 4; ++e) c[0] |= enc1(qlog(src[e]))     << (8 * e);
    #pragma unroll
    for (int e = 0; e < 4; ++e) c[1] |= enc1(qlog(src[4 + e])) << (8 * e);
    wsq[gid] = c;
    __threadfence();
}

template<bool USE_WS>
__global__ __launch_bounds__(512, 4) void lqw_gemm(
    const float* __restrict__ in,    // [262144][256]
    const float* __restrict__ w,     // [256][256]
    const float* __restrict__ bias,  // [256]
    const u32v2* __restrict__ wsq,
    float* __restrict__ out)         // [262144][256]
{
    __shared__ __align__(16) char smem[2 * TILEB];   // 33792 B
    const int tid  = threadIdx.x;
    const int lane = tid & 63;
    const int wv   = tid >> 6;       // wave 0..7 owns 32 output cols
    const int nbase = wv * 32;
    const int lrow = lane & 15;
    const int kgrp = lane >> 4;

    // ---- quantized B codes (8 B per frag -> 32 VGPRs total) ----
    u32v2 bc[2][8];
    if (USE_WS) {
        #pragma unroll
        for (int nt = 0; nt < 2; ++nt)
            #pragma unroll
            for (int kt = 0; kt < 8; ++kt)
                bc[nt][kt] = wsq[(size_t)((wv * 2 + nt) * 8 + kt) * 64 + lane];
    } else {
        #pragma unroll
        for (int nt = 0; nt < 2; ++nt) {
            const float* wrow = w + (size_t)(nbase + nt * 16 + lrow) * 256;
            #pragma unroll
            for (int kt = 0; kt < 8; ++kt) {
                u32v2 c = (u32v2){0, 0};
                #pragma unroll
                for (int e = 0; e < 4; ++e)
                    c[0] |= enc1(qlog(wrow[kt * 32 + kgrp * 8 + e])) << (8 * e);
                #pragma unroll
                for (int e = 0; e < 4; ++e)
                    c[1] |= enc1(qlog(wrow[kt * 32 + kgrp * 8 + 4 + e])) << (8 * e);
                bc[nt][kt] = c;
            }
        }
    }
    // bias for swapped-D layout: lane holds n = nbase + nt*16 + kgrp*4 + rg
    f32x4 bv[2];
    #pragma unroll
    for (int nt = 0; nt < 2; ++nt)
        bv[nt] = *(const f32x4*)(bias + nbase + nt * 16 + kgrp * 4);

    const int mt0 = blockIdx.x * ITERS;

    #define LOAD_TILE(S, mt) do {                                          \
        const f32x4* _s = (const f32x4*)(in + (size_t)(mt) * (MROWS*256)); \
        S[0] = _s[0*512 + tid]; S[1] = _s[1*512 + tid];                    \
        S[2] = _s[2*512 + tid]; S[3] = _s[3*512 + tid];                    \
    } while (0)

    #define WRITE_TILE(b, S) do {                                          \
        char* _d = smem + (b) * TILEB;                                     \
        _Pragma("unroll")                                                  \
        for (int r = 0; r < 4; ++r) {                                      \
            int j = r * 512 + tid;                                         \
            bf16x4 v;                                                      \
            v[0] = (__bf16)S[r][0]; v[1] = (__bf16)S[r][1];                \
            v[2] = (__bf16)S[r][2]; v[3] = (__bf16)S[r][3];                \
            *(bf16x4*)(_d + (j >> 6) * ROWB + (j & 63) * 8) = v;           \
        }                                                                  \
    } while (0)

    #define COMPUTE(b, mt) do {                                                             \
        const char* base = smem + (b) * TILEB;                                              \
        f32x4 acc[2][2];                                                                    \
        _Pragma("unroll")                                                                   \
        for (int mi = 0; mi < 2; ++mi)                                                      \
            _Pragma("unroll")                                                               \
            for (int nt = 0; nt < 2; ++nt) acc[mi][nt] = bv[nt];                            \
        _Pragma("unroll")                                                                   \
        for (int kt = 0; kt < 8; ++kt) {                                                    \
            bf16x8 a0 = *(const bf16x8*)(base + (size_t)lrow * ROWB + kt * 64 + kgrp * 16); \
            bf16x8 a1 = *(const bf16x8*)(base + (size_t)(16 + lrow) * ROWB + kt * 64 + kgrp * 16); \
            bf16x8 b0 = dec_frag(bc[0][kt][0], bc[0][kt][1]);                               \
            bf16x8 b1 = dec_frag(bc[1][kt][0], bc[1][kt][1]);                               \
            acc[0][0] = __builtin_amdgcn_mfma_f32_16x16x32_bf16(b0, a0, acc[0][0], 0, 0, 0); \
            acc[0][1] = __builtin_amdgcn_mfma_f32_16x16x32_bf16(b1, a0, acc[0][1], 0, 0, 0); \
            acc[1][0] = __builtin_amdgcn_mfma_f32_16x16x32_bf16(b0, a1, acc[1][0], 0, 0, 0); \
            acc[1][1] = __builtin_amdgcn_mfma_f32_16x16x32_bf16(b1, a1, acc[1][1], 0, 0, 0); \
        }                                                                                   \
        _Pragma("unroll")                                                                   \
        for (int mi = 0; mi < 2; ++mi) {                                                    \
            float* orow = out + (size_t)((mt) * 32 + mi * 16 + lrow) * 256 + nbase + kgrp * 4; \
            *(f32x4*)(orow)      = acc[mi][0];                                              \
            *(f32x4*)(orow + 16) = acc[mi][1];                                              \
        }                                                                                   \
    } while (0)

    // ---- 2-deep pipelined prologue ----
    f32x4 sA[4], sB[4];
    LOAD_TILE(sA, mt0);
    LOAD_TILE(sB, mt0 + 1);
    WRITE_TILE(0, sA);
    LOAD_TILE(sA, mt0 + 2);
    BAR();

    #pragma unroll 1
    for (int t = 0; t < ITERS; t += 2) {
        // even phase: compute tile t from buf0; stage t+1; prefetch t+3
        WRITE_TILE(1, sB);
        if (t + 3 < ITERS) LOAD_TILE(sB, mt0 + t + 3);
        COMPUTE(0, mt0 + t);
        BAR();
        // odd phase: compute tile t+1 from buf1; stage t+2; prefetch t+4
        if (t + 2 < ITERS) WRITE_TILE(0, sA);
        if (t + 4 < ITERS) LOAD_TILE(sA, mt0 + t + 4);
        COMPUTE(1, mt0 + t + 1);
        BAR();
    }
}

extern "C" void kernel_launch(void* const* d_in, const int* in_sizes, int n_in,
                              void* d_out, int out_size, void* d_ws, size_t ws_size,
                              hipStream_t stream) {
    const float* in_p   = (const float*)d_in[0];
    const float* w_p    = (const float*)d_in[1];
    const float* bias_p = (const float*)d_in[2];
    float* out_p        = (float*)d_out;
    if (ws_size >= WSB) {
        u32v2* wsq = (u32v2*)d_ws;
        lqw_quant<<<32, 256, 0, stream>>>(w_p, wsq);
        lqw_gemm<true><<<GRID, 512, 0, stream>>>(in_p, w_p, bias_p, wsq, out_p);
    } else {
        lqw_gemm<false><<<GRID, 512, 0, stream>>>(in_p, w_p, bias_p, nullptr, out_p);
    }
}

// Round 14
// 115.609 us; speedup vs baseline: 6.5711x; 1.1830x over previous
//
#include <hip/hip_runtime.h>
#include <hip/hip_bf16.h>
#include <stdint.h>

typedef float  f32x4  __attribute__((ext_vector_type(4)));
typedef __bf16 bf16x8 __attribute__((ext_vector_type(8)));
typedef unsigned int u32;
typedef u32 u32v2 __attribute__((ext_vector_type(2)));

#define GRID   1024
#define MROWS  32
#define ITERS  8           // GRID * ITERS * MROWS = 262144 rows
#define TILEB  (MROWS * 1024)   // f32 tile: 32 rows x 1024 B, LINEAR (gload_lds req)
#define WSB    65536            // code table: 8192 frags * 8 B

// exp_proj onto {sign(w) * 0.25 * 2^k, k=0..4}; boundaries at 0.25*2^(k+0.5)
__device__ __forceinline__ float qlog(float v) {
    float a = fabsf(v);
    int k = (a >= 0.35355339059327373f)
          + (a >= 0.70710678118654746f)
          + (a >= 1.41421356237309515f)
          + (a >= 2.82842712474619029f);
    float q = 0.25f * (float)(1 << k);
    return (v == 0.0f) ? 0.0f : copysignf(q, v);
}

// 1-byte code: sign<<7 | (bf16_exponent - 64). Grid exps 125..129 -> 61..65.
__device__ __forceinline__ u32 enc1(float q) {
    u32 b16 = __float_as_uint(q) >> 16;
    return b16 ? (((b16 >> 8) & 0x80u) | (((b16 >> 7) & 0xFFu) - 64u)) : 0u;
}
// decode 2 codes in u16 lanes: bf16 = (code + (code&0x80) + 64) << 7
__device__ __forceinline__ u32 dec2(u32 d) {
    u32 t = d & 0x00800080u;
    return (d + t + 0x00400040u) << 7;
}
__device__ __forceinline__ bf16x8 dec_frag(u32 c0, u32 c1) {
#if __has_builtin(__builtin_amdgcn_perm)
    u32 d0 = __builtin_amdgcn_perm(0u, c0, 0x0C010C00u);
    u32 d1 = __builtin_amdgcn_perm(0u, c0, 0x0C030C02u);
    u32 d2 = __builtin_amdgcn_perm(0u, c1, 0x0C010C00u);
    u32 d3 = __builtin_amdgcn_perm(0u, c1, 0x0C030C02u);
#else
    u32 d0 = (c0 & 0xFFu) | ((c0 & 0xFF00u) << 8);
    u32 d1 = ((c0 >> 16) & 0xFFu) | ((c0 & 0xFF000000u) >> 8);
    u32 d2 = (c1 & 0xFFu) | ((c1 & 0xFF00u) << 8);
    u32 d3 = ((c1 >> 16) & 0xFFu) | ((c1 & 0xFF000000u) >> 8);
#endif
    union { u32 u[4]; bf16x8 v; } u_;
    u_.u[0] = dec2(d0); u_.u[1] = dec2(d1);
    u_.u[2] = dec2(d2); u_.u[3] = dec2(d3);
    return u_.v;
}

// async global->LDS, 16 B/lane; LDS dest wave-uniform base + lane*16
__device__ __forceinline__ void gload16(const float* g, char* l) {
#if __has_builtin(__builtin_amdgcn_global_load_lds)
    __builtin_amdgcn_global_load_lds(
        (const __attribute__((address_space(1))) u32*)g,
        (__attribute__((address_space(3))) u32*)l, 16, 0, 0);
#else
    const int lane = threadIdx.x & 63;
    *(f32x4*)(l + lane * 16) = *(const f32x4*)(g + lane * 4);
#endif
}

// kernel 1: quantize weight -> 1-byte-code frag table (R12, proven).
// frag f = (ntile*8 + kt)*64 + lane ; codes of w_q[n][k0..k0+7],
// n = ntile*16 + (lane&15), k0 = kt*32 + (lane>>4)*8.
__global__ __launch_bounds__(256) void lqw_quant(
    const float* __restrict__ w, u32v2* __restrict__ wsq)
{
    const int gid  = blockIdx.x * 256 + threadIdx.x;
    const int lane = gid & 63;
    const int kt   = (gid >> 6) & 7;
    const int ntv  = gid >> 9;
    const float* src = w + (size_t)(ntv * 16 + (lane & 15)) * 256
                         + kt * 32 + (lane >> 4) * 8;
    u32v2 c = (u32v2){0, 0};
    #pragma unroll
    for (int e = 0; e < 4; ++e) c[0] |= enc1(qlog(src[e]))     << (8 * e);
    #pragma unroll
    for (int e = 0; e < 4; ++e) c[1] |= enc1(qlog(src[4 + e])) << (8 * e);
    wsq[gid] = c;
    __threadfence();
}

template<bool USE_WS>
__global__ __launch_bounds__(512, 4) void lqw_gemm(
    const float* __restrict__ in,    // [262144][256]
    const float* __restrict__ w,     // [256][256]
    const float* __restrict__ bias,  // [256]
    const u32v2* __restrict__ wsq,
    float* __restrict__ out)         // [262144][256]
{
    __shared__ __align__(16) char smem[2 * TILEB];   // 65536 B -> 2 blocks/CU
    const int tid  = threadIdx.x;
    const int lane = tid & 63;
    const int wv   = tid >> 6;       // wave 0..7 owns 32 output cols
    const int nbase = wv * 32;
    const int lrow = lane & 15;
    const int kgrp = lane >> 4;
    const int s    = lrow & 7;       // per-row XOR swizzle key (16B units)
    // consumer LDS offsets for the two 16B halves of each 32B A-slice
    const int o0 = ((kgrp * 2)     ^ s) * 16;
    const int o1 = ((kgrp * 2 + 1) ^ s) * 16;

    // ---- quantized B codes (8 B per frag -> 32 VGPRs) ----
    u32v2 bc[2][8];
    if (USE_WS) {
        #pragma unroll
        for (int nt = 0; nt < 2; ++nt)
            #pragma unroll
            for (int kt = 0; kt < 8; ++kt)
                bc[nt][kt] = wsq[(size_t)((wv * 2 + nt) * 8 + kt) * 64 + lane];
    } else {
        #pragma unroll
        for (int nt = 0; nt < 2; ++nt) {
            const float* wrow = w + (size_t)(nbase + nt * 16 + lrow) * 256;
            #pragma unroll
            for (int kt = 0; kt < 8; ++kt) {
                u32v2 c = (u32v2){0, 0};
                #pragma unroll
                for (int e = 0; e < 4; ++e)
                    c[0] |= enc1(qlog(wrow[kt * 32 + kgrp * 8 + e])) << (8 * e);
                #pragma unroll
                for (int e = 0; e < 4; ++e)
                    c[1] |= enc1(qlog(wrow[kt * 32 + kgrp * 8 + 4 + e])) << (8 * e);
                bc[nt][kt] = c;
            }
        }
    }
    // bias for swapped-D layout: lane holds n = nbase + nt*16 + kgrp*4 + rg
    f32x4 bv[2];
    #pragma unroll
    for (int nt = 0; nt < 2; ++nt)
        bv[nt] = *(const f32x4*)(bias + nbase + nt * 16 + kgrp * 4);

    const int mt0 = blockIdx.x * ITERS;

    // stage tile mt -> buffer b: 4 rows per wave, 1 KB per gload instr.
    // global source column-unit is XOR-swizzled by row&7; LDS stays linear.
    #define STAGE(b, mt) do {                                               \
        char* _d = smem + (b) * TILEB;                                      \
        _Pragma("unroll")                                                   \
        for (int j = 0; j < 4; ++j) {                                       \
            const int r = wv * 4 + j;                                       \
            const float* _s = in + ((size_t)(mt) * MROWS + r) * 256         \
                                 + ((lane ^ (r & 7)) << 2);                 \
            gload16(_s, _d + r * 1024);                                     \
        }                                                                   \
    } while (0)

    #define COMPUTE(b, mt) do {                                                             \
        const char* base = smem + (b) * TILEB;                                              \
        f32x4 acc[2][2];                                                                    \
        _Pragma("unroll")                                                                   \
        for (int mi = 0; mi < 2; ++mi)                                                      \
            _Pragma("unroll")                                                               \
            for (int nt = 0; nt < 2; ++nt) acc[mi][nt] = bv[nt];                            \
        const char* row0 = base + (size_t)lrow * 1024;                                      \
        const char* row1 = base + (size_t)(16 + lrow) * 1024;                               \
        _Pragma("unroll")                                                                   \
        for (int kt = 0; kt < 8; ++kt) {                                                    \
            f32x4 lo0 = *(const f32x4*)(row0 + kt * 128 + o0);                              \
            f32x4 hi0 = *(const f32x4*)(row0 + kt * 128 + o1);                              \
            f32x4 lo1 = *(const f32x4*)(row1 + kt * 128 + o0);                              \
            f32x4 hi1 = *(const f32x4*)(row1 + kt * 128 + o1);                              \
            bf16x8 a0, a1;                                                                  \
            _Pragma("unroll")                                                               \
            for (int e = 0; e < 4; ++e) {                                                   \
                a0[e] = (__bf16)lo0[e]; a0[4 + e] = (__bf16)hi0[e];                         \
                a1[e] = (__bf16)lo1[e]; a1[4 + e] = (__bf16)hi1[e];                         \
            }                                                                               \
            bf16x8 b0 = dec_frag(bc[0][kt][0], bc[0][kt][1]);                               \
            bf16x8 b1 = dec_frag(bc[1][kt][0], bc[1][kt][1]);                               \
            acc[0][0] = __builtin_amdgcn_mfma_f32_16x16x32_bf16(b0, a0, acc[0][0], 0, 0, 0); \
            acc[0][1] = __builtin_amdgcn_mfma_f32_16x16x32_bf16(b1, a0, acc[0][1], 0, 0, 0); \
            acc[1][0] = __builtin_amdgcn_mfma_f32_16x16x32_bf16(b0, a1, acc[1][0], 0, 0, 0); \
            acc[1][1] = __builtin_amdgcn_mfma_f32_16x16x32_bf16(b1, a1, acc[1][1], 0, 0, 0); \
        }                                                                                   \
        _Pragma("unroll")                                                                   \
        for (int mi = 0; mi < 2; ++mi) {                                                    \
            float* orow = out + (size_t)((mt) * MROWS + mi * 16 + lrow) * 256 + nbase + kgrp * 4; \
            *(f32x4*)(orow)      = acc[mi][0];                                              \
            *(f32x4*)(orow + 16) = acc[mi][1];                                              \
        }                                                                                   \
    } while (0)

    // ---- prologue: stage tile 0, full drain, publish ----
    STAGE(0, mt0);
    asm volatile("s_waitcnt vmcnt(0)" ::: "memory");
    __builtin_amdgcn_s_barrier();

    #pragma unroll 1
    for (int t = 0; t < ITERS; ++t) {
        const int b = t & 1;
        if (t + 1 < ITERS) STAGE(b ^ 1, mt0 + t + 1);   // 4 fire-and-forget gloads
        // pin: all 4 gloads issue BEFORE any of COMPUTE's vmem stores,
        // so the vmcnt(4) below reliably covers exactly the 4 newest stores.
        __builtin_amdgcn_sched_barrier(0);
        COMPUTE(b, mt0 + t);                            // ds_read + MFMA + 4 stores
        // publish buf b^1: 4 newest vmem ops are this iter's 4 stores ->
        // vmcnt(4) completes the gloads (and older stores) without draining them.
        asm volatile("s_waitcnt vmcnt(4) lgkmcnt(0)" ::: "memory");
        __builtin_amdgcn_sched_barrier(0);
        __builtin_amdgcn_s_barrier();
    }
}

extern "C" void kernel_launch(void* const* d_in, const int* in_sizes, int n_in,
                              void* d_out, int out_size, void* d_ws, size_t ws_size,
                              hipStream_t stream) {
    const float* in_p   = (const float*)d_in[0];
    const float* w_p    = (const float*)d_in[1];
    const float* bias_p = (const float*)d_in[2];
    float* out_p        = (float*)d_out;
    if (ws_size >= WSB) {
        u32v2* wsq = (u32v2*)d_ws;
        lqw_quant<<<32, 256, 0, stream>>>(w_p, wsq);
        lqw_gemm<true><<<GRID, 512, 0, stream>>>(in_p, w_p, bias_p, wsq, out_p);
    } else {
        lqw_gemm<false><<<GRID, 512, 0, stream>>>(in_p, w_p, bias_p, nullptr, out_p);
    }
}

// Round 15
// 115.480 us; speedup vs baseline: 6.5784x; 1.0011x over previous
//
#include <hip/hip_runtime.h>
#include <hip/hip_bf16.h>
#include <stdint.h>

typedef float  f32x4  __attribute__((ext_vector_type(4)));
typedef __bf16 bf16x8 __attribute__((ext_vector_type(8)));
typedef unsigned int u32;
typedef u32 u32v2 __attribute__((ext_vector_type(2)));

#define GRID   1024
#define TROWS  16               // rows per tile
#define ITERS  16               // GRID * ITERS * TROWS = 262144 rows
#define TILEB  (TROWS * 1024)   // 16 KB f32 tile, LINEAR (gload_lds req)
#define NBUF   4                // 64 KB LDS ring -> 2 blocks/CU
#define WSB    65536            // code table: 8192 frags * 8 B

// exp_proj onto {sign(w) * 0.25 * 2^k, k=0..4}; boundaries at 0.25*2^(k+0.5)
__device__ __forceinline__ float qlog(float v) {
    float a = fabsf(v);
    int k = (a >= 0.35355339059327373f)
          + (a >= 0.70710678118654746f)
          + (a >= 1.41421356237309515f)
          + (a >= 2.82842712474619029f);
    float q = 0.25f * (float)(1 << k);
    return (v == 0.0f) ? 0.0f : copysignf(q, v);
}

// 1-byte code: sign<<7 | (bf16_exponent - 64). Grid exps 125..129 -> 61..65.
__device__ __forceinline__ u32 enc1(float q) {
    u32 b16 = __float_as_uint(q) >> 16;
    return b16 ? (((b16 >> 8) & 0x80u) | (((b16 >> 7) & 0xFFu) - 64u)) : 0u;
}
// decode 2 codes in u16 lanes: bf16 = (code + (code&0x80) + 64) << 7
__device__ __forceinline__ u32 dec2(u32 d) {
    u32 t = d & 0x00800080u;
    return (d + t + 0x00400040u) << 7;
}
__device__ __forceinline__ bf16x8 dec_frag(u32 c0, u32 c1) {
#if __has_builtin(__builtin_amdgcn_perm)
    u32 d0 = __builtin_amdgcn_perm(0u, c0, 0x0C010C00u);
    u32 d1 = __builtin_amdgcn_perm(0u, c0, 0x0C030C02u);
    u32 d2 = __builtin_amdgcn_perm(0u, c1, 0x0C010C00u);
    u32 d3 = __builtin_amdgcn_perm(0u, c1, 0x0C030C02u);
#else
    u32 d0 = (c0 & 0xFFu) | ((c0 & 0xFF00u) << 8);
    u32 d1 = ((c0 >> 16) & 0xFFu) | ((c0 & 0xFF000000u) >> 8);
    u32 d2 = (c1 & 0xFFu) | ((c1 & 0xFF00u) << 8);
    u32 d3 = ((c1 >> 16) & 0xFFu) | ((c1 & 0xFF000000u) >> 8);
#endif
    union { u32 u[4]; bf16x8 v; } u_;
    u_.u[0] = dec2(d0); u_.u[1] = dec2(d1);
    u_.u[2] = dec2(d2); u_.u[3] = dec2(d3);
    return u_.v;
}

// async global->LDS, 16 B/lane; LDS dest wave-uniform base + lane*16
__device__ __forceinline__ void gload16(const float* g, char* l) {
#if __has_builtin(__builtin_amdgcn_global_load_lds)
    __builtin_amdgcn_global_load_lds(
        (const __attribute__((address_space(1))) u32*)g,
        (__attribute__((address_space(3))) u32*)l, 16, 0, 0);
#else
    const int lane = threadIdx.x & 63;
    *(f32x4*)(l + lane * 16) = *(const f32x4*)(g + lane * 4);
#endif
}

// kernel 1: quantize weight -> 1-byte-code frag table.
// frag f = (ntile*8 + kt)*64 + lane ; codes of w_q[n][k0..k0+7],
// n = ntile*16 + (lane&15), k0 = kt*32 + (lane>>4)*8.
__global__ __launch_bounds__(256) void lqw_quant(
    const float* __restrict__ w, u32v2* __restrict__ wsq)
{
    const int gid  = blockIdx.x * 256 + threadIdx.x;
    const int lane = gid & 63;
    const int kt   = (gid >> 6) & 7;
    const int ntv  = gid >> 9;
    const float* src = w + (size_t)(ntv * 16 + (lane & 15)) * 256
                         + kt * 32 + (lane >> 4) * 8;
    u32v2 c = (u32v2){0, 0};
    #pragma unroll
    for (int e = 0; e < 4; ++e) c[0] |= enc1(qlog(src[e]))     << (8 * e);
    #pragma unroll
    for (int e = 0; e < 4; ++e) c[1] |= enc1(qlog(src[4 + e])) << (8 * e);
    wsq[gid] = c;
    __threadfence();
}

template<bool USE_WS>
__global__ __launch_bounds__(512, 4) void lqw_gemm(
    const float* __restrict__ in,    // [262144][256]
    const float* __restrict__ w,     // [256][256]
    const float* __restrict__ bias,  // [256]
    const u32v2* __restrict__ wsq,
    float* __restrict__ out)         // [262144][256]
{
    __shared__ __align__(16) char smem[NBUF * TILEB];   // 65536 B
    const int tid  = threadIdx.x;
    const int lane = tid & 63;
    const int wv   = tid >> 6;       // wave 0..7 owns 32 output cols
    const int nbase = wv * 32;
    const int lrow = lane & 15;
    const int kgrp = lane >> 4;
    const int s    = lrow & 7;       // per-row XOR swizzle key (16B units)
    const int o0 = ((kgrp * 2)     ^ s) * 16;
    const int o1 = ((kgrp * 2 + 1) ^ s) * 16;

    // ---- quantized B codes (8 B per frag -> 32 VGPRs) ----
    u32v2 bc[2][8];
    if (USE_WS) {
        #pragma unroll
        for (int nt = 0; nt < 2; ++nt)
            #pragma unroll
            for (int kt = 0; kt < 8; ++kt)
                bc[nt][kt] = wsq[(size_t)((wv * 2 + nt) * 8 + kt) * 64 + lane];
    } else {
        #pragma unroll
        for (int nt = 0; nt < 2; ++nt) {
            const float* wrow = w + (size_t)(nbase + nt * 16 + lrow) * 256;
            #pragma unroll
            for (int kt = 0; kt < 8; ++kt) {
                u32v2 c = (u32v2){0, 0};
                #pragma unroll
                for (int e = 0; e < 4; ++e)
                    c[0] |= enc1(qlog(wrow[kt * 32 + kgrp * 8 + e])) << (8 * e);
                #pragma unroll
                for (int e = 0; e < 4; ++e)
                    c[1] |= enc1(qlog(wrow[kt * 32 + kgrp * 8 + 4 + e])) << (8 * e);
                bc[nt][kt] = c;
            }
        }
    }
    // bias for swapped-D layout: lane holds n = nbase + nt*16 + kgrp*4 + rg
    f32x4 bv[2];
    #pragma unroll
    for (int nt = 0; nt < 2; ++nt)
        bv[nt] = *(const f32x4*)(bias + nbase + nt * 16 + kgrp * 4);

    const int mt0 = blockIdx.x * ITERS;

    // stage 16-row tile mt -> ring buffer: 2 rows per wave, 1 KB per gload.
    // global source column-unit XOR-swizzled by row&7; LDS stays linear.
    #define STAGE(bi, mt) do {                                              \
        char* _d = smem + (bi) * TILEB;                                     \
        _Pragma("unroll")                                                   \
        for (int j = 0; j < 2; ++j) {                                       \
            const int r = wv * 2 + j;                                       \
            const float* _s = in + ((size_t)(mt) * TROWS + r) * 256         \
                                 + ((lane ^ (r & 7)) << 2);                 \
            gload16(_s, _d + r * 1024);                                     \
        }                                                                   \
    } while (0)

    #define COMPUTE(bi, mt) do {                                                            \
        const char* row0 = smem + (bi) * TILEB + (size_t)lrow * 1024;                       \
        f32x4 acc[2];                                                                       \
        acc[0] = bv[0]; acc[1] = bv[1];                                                     \
        _Pragma("unroll")                                                                   \
        for (int kt = 0; kt < 8; ++kt) {                                                    \
            f32x4 lo = *(const f32x4*)(row0 + kt * 128 + o0);                               \
            f32x4 hi = *(const f32x4*)(row0 + kt * 128 + o1);                               \
            bf16x8 a0;                                                                      \
            _Pragma("unroll")                                                               \
            for (int e = 0; e < 4; ++e) { a0[e] = (__bf16)lo[e]; a0[4 + e] = (__bf16)hi[e]; } \
            bf16x8 b0 = dec_frag(bc[0][kt][0], bc[0][kt][1]);                               \
            bf16x8 b1 = dec_frag(bc[1][kt][0], bc[1][kt][1]);                               \
            acc[0] = __builtin_amdgcn_mfma_f32_16x16x32_bf16(b0, a0, acc[0], 0, 0, 0);      \
            acc[1] = __builtin_amdgcn_mfma_f32_16x16x32_bf16(b1, a0, acc[1], 0, 0, 0);      \
        }                                                                                   \
        float* orow = out + (size_t)((mt) * TROWS + lrow) * 256 + nbase + kgrp * 4;         \
        *(f32x4*)(orow)      = acc[0];                                                      \
        *(f32x4*)(orow + 16) = acc[1];                                                      \
    } while (0)

    // ---- prologue: stage tiles 0,1,2; publish buf0 (allow g1,g2 = 4 in flight)
    STAGE(0, mt0);
    STAGE(1, mt0 + 1);
    STAGE(2, mt0 + 2);
    asm volatile("s_waitcnt vmcnt(4)" ::: "memory");
    __builtin_amdgcn_s_barrier();

    #pragma unroll 1
    for (int t = 0; t < ITERS; ++t) {
        if (t + 3 < ITERS) STAGE((t + 3) & (NBUF - 1), mt0 + t + 3);  // 2 gloads
        __builtin_amdgcn_sched_barrier(0);   // pin gloads before COMPUTE's stores
        COMPUTE(t & (NBUF - 1), mt0 + t);    // 16 ds_read + 16 MFMA + 2 stores
        // steady state (oldest->newest): g(t+1),s(t-2),g(t+2),s(t-1),g(t+3),s(t).
        // vmcnt(6) allows the newest 6 ops -> forces g(t+2) and older complete;
        // buf(t+1) (needed next iter) was staged >=1.5 iters ago -> zero-cost.
        asm volatile("s_waitcnt vmcnt(6) lgkmcnt(0)" ::: "memory");
        __builtin_amdgcn_sched_barrier(0);
        __builtin_amdgcn_s_barrier();
    }
}

extern "C" void kernel_launch(void* const* d_in, const int* in_sizes, int n_in,
                              void* d_out, int out_size, void* d_ws, size_t ws_size,
                              hipStream_t stream) {
    const float* in_p   = (const float*)d_in[0];
    const float* w_p    = (const float*)d_in[1];
    const float* bias_p = (const float*)d_in[2];
    float* out_p        = (float*)d_out;
    if (ws_size >= WSB) {
        u32v2* wsq = (u32v2*)d_ws;
        lqw_quant<<<32, 256, 0, stream>>>(w_p, wsq);
        lqw_gemm<true><<<GRID, 512, 0, stream>>>(in_p, w_p, bias_p, wsq, out_p);
    } else {
        lqw_gemm<false><<<GRID, 512, 0, stream>>>(in_p, w_p, bias_p, nullptr, out_p);
    }
}